// Round 6
// baseline (2092.800 us; speedup 1.0000x reference)
//
#include <hip/hip_runtime.h>
#include <cstddef>

typedef _Float16 f16x8 __attribute__((ext_vector_type(8)));
typedef float f32x16 __attribute__((ext_vector_type(16)));
typedef float f32x4 __attribute__((ext_vector_type(4)));
typedef unsigned short ushort_t;

#define SCL 4096.f
#define ISCL (1.f / 4096.f)
#define NSEG 7168
#define NNODE 8192

enum { EP_NONE = 0, EP_BIAS = 1, EP_RAWP = 2, EP_NL1 = 3, EP_NL3 = 4 };

#define PHASE_BARRIER() do { asm volatile("s_waitcnt lgkmcnt(0)" ::: "memory"); \
                             __builtin_amdgcn_s_barrier(); } while (0)

// ---- prepack W[k][n] fp32 -> 32x32-fragment-native f16 hi/lo -------------
// P[((kc*NT + nt)*64 + lane)*16 + j] : lane = ((k>>3)&1)*32 + (n&31), j = k&7
__global__ __launch_bounds__(256)
void prepack(const float* __restrict__ W, ushort_t* __restrict__ P,
             int koff, int kcnt, int N) {
  int idx = blockIdx.x * 256 + threadIdx.x;
  if (idx >= kcnt * N) return;
  int kl = idx / N, n = idx - kl * N;
  float wv = W[idx];
  _Float16 h = (_Float16)wv;
  _Float16 l = (_Float16)((wv - (float)h) * SCL);
  int k = koff + kl;
  int NT = N >> 5;
  size_t o = ((((size_t)(k >> 4)) * NT + (n >> 5)) * 64 + ((k >> 3) & 1) * 32 + (n & 31)) * 16 + (k & 7);
  P[o] = __builtin_bit_cast(ushort_t, h);
  P[o + 8] = __builtin_bit_cast(ushort_t, l);
}

// ---- v6[n] = 6 * sum_k e_b3[k] * n_w1[260+k][n] --------------------------
__global__ __launch_bounds__(256)
void v6k(const float* __restrict__ eb3, const float* __restrict__ nw1,
         float* __restrict__ v6) {
  int n = blockIdx.x * 256 + threadIdx.x;
  if (n >= 512) return;
  float a = 0.f;
  for (int k = 0; k < 512; ++k) a += eb3[k] * nw1[(size_t)(260 + k) * 512 + n];
  v6[n] = 6.f * a;
}

// ---- unified 64x128-tile MFMA GEMM (split-f16, 32x32x16), pipelined ------
template <int NCOLB, int EPI, int EDGE, int LNIN>
__global__ __launch_bounds__(256, 3)
void gemmT(const float* __restrict__ X1, int ld1, int nph1,
           const float* __restrict__ X2, int ld2, int nph2,
           const float* __restrict__ Sm, const float* __restrict__ Tm,
           const ushort_t* __restrict__ P,
           const float* __restrict__ bias, const float* __restrict__ bias2,
           const int* __restrict__ action, const float* __restrict__ wact,
           const float* __restrict__ lnmu, const float* __restrict__ lnrsd,
           const float* __restrict__ lng, const float* __restrict__ lnbn,
           float* __restrict__ Y, float* __restrict__ Yres,
           float* __restrict__ Part, int m0base) {
  constexpr int N = NCOLB * 128;
  constexpr int NT = N / 32;
  const int u = threadIdx.x;
  const int mY = blockIdx.x * 64;
  const int nB = blockIdx.y * 128;
  const int lane = u & 63, w = u >> 6, wr = w >> 1, wc = w & 1;

  __shared__ ushort_t lA[16384];          // 2 x (4096 hi + 4096 lo) ushorts
  __shared__ int eR[64], eC[64];

  if (EDGE) {
    if (u < 64) {
      int e = m0base + mY + u;
      int b = e / 42, p = e - b * 42;
      int i = p / 6, tt = p - i * 6;
      int j = tt + (tt >= i ? 1 : 0);
      eR[u] = b * 7 + i;
      eC[u] = b * 7 + j;
    }
    __syncthreads();
  }

  const int srow = u >> 2, skq = u & 3;
  const int srt = srow >> 5, srr = srow & 31;
  const int gofs0 = (((srt * 4 + skq) * 2 + 0) * 32 + (srr ^ (skq << 3))) * 8;
  const int gofs1 = gofs0 + 256;

  const float* sB = nullptr;
  const float* tB = nullptr;
  const float* x1B = nullptr;
  const float* x2B = nullptr;
  if (EDGE) {
    sB = Sm + (size_t)eR[srow] * 512 + skq * 16;
    tB = Tm + (size_t)eC[srow] * 512 + skq * 16;
  } else {
    x1B = X1 + (size_t)(mY + srow) * ld1 + skq * 16;
    if (nph2 > 0) x2B = X2 + (size_t)(mY + srow) * ld2 + skq * 16;
  }
  float mym = 0.f, myr = 0.f;
  if (LNIN) { mym = lnmu[mY + srow]; myr = lnrsd[mY + srow]; }

  float xc[16];
  auto loadx = [&](int ph) {
    if (EDGE) {
      const float* sp = sB + ph * 64;
      const float* tp = tB + ph * 64;
      #pragma unroll
      for (int q4 = 0; q4 < 4; ++q4) {
        float4 sv = *(const float4*)(sp + q4 * 4);
        float4 tv = *(const float4*)(tp + q4 * 4);
        xc[q4 * 4 + 0] = fmaxf(sv.x + tv.x, 0.f);
        xc[q4 * 4 + 1] = fmaxf(sv.y + tv.y, 0.f);
        xc[q4 * 4 + 2] = fmaxf(sv.z + tv.z, 0.f);
        xc[q4 * 4 + 3] = fmaxf(sv.w + tv.w, 0.f);
      }
    } else {
      const float* src = (ph < nph1) ? x1B + ph * 64 : x2B + (ph - nph1) * 64;
      #pragma unroll
      for (int q4 = 0; q4 < 4; ++q4)
        *(float4*)&xc[q4 * 4] = *(const float4*)(src + q4 * 4);
      if (LNIN) {
        int kb = ph * 64 + skq * 16;
        #pragma unroll
        for (int q4 = 0; q4 < 4; ++q4) {
          float4 gv = *(const float4*)(lng + kb + q4 * 4);
          float4 bv = *(const float4*)(lnbn + kb + q4 * 4);
          xc[q4 * 4 + 0] = fmaxf((xc[q4 * 4 + 0] - mym) * myr * gv.x + bv.x, 0.f);
          xc[q4 * 4 + 1] = fmaxf((xc[q4 * 4 + 1] - mym) * myr * gv.y + bv.y, 0.f);
          xc[q4 * 4 + 2] = fmaxf((xc[q4 * 4 + 2] - mym) * myr * gv.z + bv.z, 0.f);
          xc[q4 * 4 + 3] = fmaxf((xc[q4 * 4 + 3] - mym) * myr * gv.w + bv.w, 0.f);
        }
      }
    }
  };
  auto cvtwrite = [&](int b) {
    f16x8 h0, h1, l0, l1;
    #pragma unroll
    for (int j = 0; j < 8; ++j) {
      float a = xc[j], b2 = xc[8 + j];
      _Float16 ha = (_Float16)a, hb = (_Float16)b2;
      h0[j] = ha; l0[j] = (_Float16)((a - (float)ha) * SCL);
      h1[j] = hb; l1[j] = (_Float16)((b2 - (float)hb) * SCL);
    }
    const int base = b * 8192;
    *(f16x8*)&lA[base + gofs0] = h0;
    *(f16x8*)&lA[base + gofs0 + 4096] = l0;
    *(f16x8*)&lA[base + gofs1] = h1;
    *(f16x8*)&lA[base + gofs1 + 4096] = l1;
  };

  f32x16 accH[2], accL[2];
  #pragma unroll
  for (int ct = 0; ct < 2; ++ct)
    #pragma unroll
    for (int q = 0; q < 16; ++q) { accH[ct][q] = 0.f; accL[ct][q] = 0.f; }

  const int nph = nph1 + nph2;
  const int ntb = (nB >> 5) + wc * 2;

  // prologue: stage phase 0, issue phase-1 loads, prefetch B(0)
  loadx(0);
  cvtwrite(0);
  if (nph > 1) loadx(1);
  PHASE_BARRIER();
  f16x8 bhP0, blP0, bhP1, blP1;
  {
    const ushort_t* bp_ = P + ((size_t)ntb * 64 + lane) * 16;
    bhP0 = *(const f16x8*)bp_;          blP0 = *(const f16x8*)(bp_ + 8);
    bhP1 = *(const f16x8*)(bp_ + 1024); blP1 = *(const f16x8*)(bp_ + 1032);
  }

  #pragma unroll 1
  for (int ph = 0; ph < nph; ++ph) {
    if (ph + 1 < nph) {
      cvtwrite((ph + 1) & 1);          // stage next phase into other buffer
      if (ph + 2 < nph) loadx(ph + 2); // issue next-next global loads
    }
    const int lbase = (ph & 1) * 8192;
    #pragma unroll
    for (int s = 0; s < 4; ++s) {
      const int aofs = lbase + (((wr * 4 + s) * 2 + (lane >> 5)) * 32 + ((lane & 31) ^ (s << 3))) * 8;
      f16x8 ah = *(const f16x8*)&lA[aofs];
      f16x8 al = *(const f16x8*)&lA[aofs + 4096];
      f16x8 b0h = bhP0, b0l = blP0, b1h = bhP1, b1l = blP1;
      const int kcn = ph * 4 + s + 1;
      if (kcn < nph * 4) {             // prefetch next B fragments
        const ushort_t* bp_ = P + (((size_t)kcn * NT + ntb) * 64 + lane) * 16;
        bhP0 = *(const f16x8*)bp_;          blP0 = *(const f16x8*)(bp_ + 8);
        bhP1 = *(const f16x8*)(bp_ + 1024); blP1 = *(const f16x8*)(bp_ + 1032);
      }
      accH[0] = __builtin_amdgcn_mfma_f32_32x32x16_f16(ah, b0h, accH[0], 0, 0, 0);
      accL[0] = __builtin_amdgcn_mfma_f32_32x32x16_f16(ah, b0l, accL[0], 0, 0, 0);
      accL[0] = __builtin_amdgcn_mfma_f32_32x32x16_f16(al, b0h, accL[0], 0, 0, 0);
      accH[1] = __builtin_amdgcn_mfma_f32_32x32x16_f16(ah, b1h, accH[1], 0, 0, 0);
      accL[1] = __builtin_amdgcn_mfma_f32_32x32x16_f16(ah, b1l, accL[1], 0, 0, 0);
      accL[1] = __builtin_amdgcn_mfma_f32_32x32x16_f16(al, b1h, accL[1], 0, 0, 0);
    }
    if (ph + 1 < nph) PHASE_BARRIER();
  }

  // ---- epilogue: C/D col = lane&31, row = (q&3) + 8*(q>>2) + 4*(lane>>5) --
  const int col0 = nB + wc * 64 + (lane & 31);
  float v[2][16];
  #pragma unroll
  for (int ct = 0; ct < 2; ++ct) {
    float bc = (EPI == EP_NONE) ? 0.f : bias[col0 + ct * 32];
    #pragma unroll
    for (int q = 0; q < 16; ++q)
      v[ct][q] = accH[ct][q] + accL[ct][q] * ISCL + bc;
  }

  if (EPI == EP_NL1) {
    #pragma unroll
    for (int q = 0; q < 16; ++q) {
      int m = mY + wr * 32 + (q & 3) + 8 * (q >> 2) + 4 * (lane >> 5);
      if (m < NSEG) {                  // agg-derived bias only where edges exist
        v[0][q] += bias2[col0];
        v[1][q] += bias2[col0 + 32];
      }
      if (action != nullptr) {
        const float* wrp = wact + (size_t)(256 + action[m >> 3]) * 512;
        v[0][q] += wrp[col0];
        v[1][q] += wrp[col0 + 32];
      }
    }
    #pragma unroll
    for (int ct = 0; ct < 2; ++ct)
      #pragma unroll
      for (int q = 0; q < 16; ++q) v[ct][q] = fmaxf(v[ct][q], 0.f);
  }

  if (EPI == EP_RAWP) {
    float sv[16], qv[16];
    #pragma unroll
    for (int q = 0; q < 16; ++q) {
      sv[q] = v[0][q] + v[1][q];
      qv[q] = v[0][q] * v[0][q] + v[1][q] * v[1][q];
    }
    #pragma unroll
    for (int mm = 1; mm <= 16; mm <<= 1) {
      #pragma unroll
      for (int q = 0; q < 16; ++q) {
        sv[q] += __shfl_xor(sv[q], mm);
        qv[q] += __shfl_xor(qv[q], mm);
      }
    }
    if ((lane & 31) == 0) {
      #pragma unroll
      for (int q = 0; q < 16; ++q) {
        int m = mY + wr * 32 + (q & 3) + 8 * (q >> 2) + 4 * (lane >> 5);
        Part[(size_t)m * 16 + blockIdx.y * 2 + wc] = sv[q];
        Part[(size_t)m * 16 + 8 + blockIdx.y * 2 + wc] = qv[q];
      }
    }
  }

  #pragma unroll
  for (int ct = 0; ct < 2; ++ct) {
    #pragma unroll
    for (int q = 0; q < 16; ++q) {
      int m = mY + wr * 32 + (q & 3) + 8 * (q >> 2) + 4 * (lane >> 5);
      float z = v[ct][q];
      Y[(size_t)m * N + col0 + ct * 32] = z;
      if (EPI == EP_NL3) Yres[(size_t)m * N + col0 + ct * 32] += z;
    }
  }
}

// ---- per-row LN stats from 8 column-block partials -----------------------
__global__ __launch_bounds__(256)
void rowstats(const float* __restrict__ Part, float* __restrict__ mu,
              float* __restrict__ rsd, int M) {
  int m = blockIdx.x * 256 + threadIdx.x;
  if (m >= M) return;
  const float* p = Part + (size_t)m * 16;
  float S = 0.f, Q = 0.f;
  #pragma unroll
  for (int i = 0; i < 8; ++i) { S += p[i]; Q += p[8 + i]; }
  float mm = S * (1.f / 512.f);
  mu[m] = mm;
  rsd[m] = rsqrtf(Q * (1.f / 512.f) - mm * mm + 1e-5f);
}

// ---- apply LN+relu to 6 H2 rows and sum per segment ----------------------
__global__ __launch_bounds__(256)
void h2_sum_ln(const float* __restrict__ H2, const float* __restrict__ mu,
               const float* __restrict__ rsd, const float* __restrict__ g,
               const float* __restrict__ bn, float* __restrict__ SS, int nrows) {
  int id = blockIdx.x * 256 + threadIdx.x;
  if (id >= nrows * 128) return;
  int ln = id >> 7, c4 = (id & 127) * 4;
  float4 gv = *(const float4*)(g + c4);
  float4 bv = *(const float4*)(bn + c4);
  float ax = 0.f, ay = 0.f, az = 0.f, aw = 0.f;
  #pragma unroll
  for (int r = 0; r < 6; ++r) {
    int row = ln * 6 + r;
    float4 y = *(const float4*)(H2 + (size_t)row * 512 + c4);
    float m = mu[row], rs = rsd[row];
    ax += fmaxf((y.x - m) * rs * gv.x + bv.x, 0.f);
    ay += fmaxf((y.y - m) * rs * gv.y + bv.y, 0.f);
    az += fmaxf((y.z - m) * rs * gv.z + bv.z, 0.f);
    aw += fmaxf((y.w - m) * rs * gv.w + bv.w, 0.f);
  }
  float4 o; o.x = ax; o.y = ay; o.z = az; o.w = aw;
  *(float4*)(SS + (size_t)ln * 512 + c4) = o;
}

// ---- launcher ------------------------------------------------------------
extern "C" void kernel_launch(void* const* d_in, const int* in_sizes, int n_in,
                              void* d_out, int out_size, void* d_ws, size_t ws_size,
                              hipStream_t stream) {
  (void)in_sizes; (void)n_in; (void)out_size;
  const float* states = (const float*)d_in[0];
  const int* action = (const int*)d_in[1];
  const float* e_w1 = (const float*)d_in[2];
  const float* e_b1 = (const float*)d_in[3];
  const float* e_w2 = (const float*)d_in[4];
  const float* e_b2 = (const float*)d_in[5];
  const float* e_g = (const float*)d_in[6];
  const float* e_bn = (const float*)d_in[7];
  const float* e_w3 = (const float*)d_in[8];
  const float* e_b3 = (const float*)d_in[9];
  const float* n_w1 = (const float*)d_in[10];
  const float* n_b1 = (const float*)d_in[11];
  const float* n_w2 = (const float*)d_in[12];
  const float* n_b2 = (const float*)d_in[13];
  const float* n_g = (const float*)d_in[14];
  const float* n_bn = (const float*)d_in[15];
  const float* n_w3 = (const float*)d_in[16];
  const float* n_b3 = (const float*)d_in[17];

  float* flat = (float*)d_out;                  // [8192][256]
  float* fp = (float*)d_ws;
  float* node = fp;  fp += 2097152;             // [8192][256]
  float* SS = fp;    fp += 4194304;             // [8192][512] (tail rows stay 0)
  float* G = fp;     fp += 4194304;             // [8192][512]
  float* Sb = fp;    fp += 3670016;             // [7168][512]
  float* Tb = fp;    fp += 3670016;             // [7168][512]
  float* Mbuf = fp;  fp += 262144;              // [512][512]  e_w3 @ n_w1g
  float* v6 = fp;    fp += 512;
  float* muE = fp;   fp += 43008;
  float* rsdE = fp;  fp += 43008;
  float* muN = fp;   fp += 8192;
  float* rsdN = fp;  fp += 8192;
  float* PartE = fp; fp += 688128;              // [43008][16]
  float* PartN = fp; fp += 131072;              // [8192][16]
  ushort_t* us = (ushort_t*)fp;
  ushort_t* PeWab = us;  us += 524288;          // K512 N512
  ushort_t* PeWc = us;   us += 262144;          // K256 N512
  ushort_t* PeW2 = us;   us += 524288;          // K512 N512
  ushort_t* Ptmp = us;   us += 524288;          // n_w1g (K512 N512) for M compute
  ushort_t* PnW1M = us;  us += 786432;          // K768 N512 (flat rows | M rows)
  ushort_t* PnW2 = us;   us += 524288;          // K512 N512
  ushort_t* PnW3 = us;   us += 262144;          // K512 N256
  float* H2raw = (float*)us;

  const size_t fixedB = (size_t)((char*)H2raw - (char*)d_ws);
  int nc = 32;
  for (int cand = 1; cand <= 32; cand <<= 1)
    if (fixedB + (43008ull / cand) * 512ull * 4ull <= ws_size) { nc = cand; break; }
  const int spc = 1024 / nc;
  const int epc = spc * 42;

  // ---- one-time prep ----
  prepack<<<1024, 256, 0, stream>>>(e_w1, PeWab, 0, 512, 512);
  prepack<<<512, 256, 0, stream>>>(e_w1 + 262144, PeWc, 0, 256, 512);
  prepack<<<1024, 256, 0, stream>>>(e_w2, PeW2, 0, 512, 512);
  prepack<<<1024, 256, 0, stream>>>(n_w1 + 133120, Ptmp, 0, 512, 512);
  prepack<<<512, 256, 0, stream>>>(n_w1, PnW1M, 0, 256, 512);
  prepack<<<1024, 256, 0, stream>>>(n_w2, PnW2, 0, 512, 512);
  prepack<<<512, 256, 0, stream>>>(n_w3, PnW3, 0, 512, 256);
  // M = e_w3 @ n_w1g  (512x512, K=512)
  gemmT<4, EP_NONE, 0, 0><<<dim3(8, 4), 256, 0, stream>>>(
      e_w3, 512, 8, nullptr, 0, 0, nullptr, nullptr, Ptmp, nullptr, nullptr,
      nullptr, nullptr, nullptr, nullptr, nullptr, nullptr, Mbuf, nullptr, nullptr, 0);
  prepack<<<1024, 256, 0, stream>>>(Mbuf, PnW1M, 256, 512, 512);
  v6k<<<2, 256, 0, stream>>>(e_b3, n_w1, v6);
  hipMemsetAsync(SS + (size_t)NSEG * 512, 0, (size_t)(NNODE - NSEG) * 512 * 4, stream);
  hipMemcpyAsync(flat, states, (size_t)NNODE * 256 * 4, hipMemcpyDeviceToDevice, stream);

  for (int round = 0; round < 8; ++round) {
    // S = flat7@Wa (+ node7@Wb) + b1 ; T = flat7@Wc
    if (round == 0)
      gemmT<4, EP_BIAS, 0, 0><<<dim3(112, 4), 256, 0, stream>>>(
          flat, 256, 4, nullptr, 0, 0, nullptr, nullptr, PeWab, e_b1, nullptr,
          nullptr, nullptr, nullptr, nullptr, nullptr, nullptr, Sb, nullptr, nullptr, 0);
    else
      gemmT<4, EP_BIAS, 0, 0><<<dim3(112, 4), 256, 0, stream>>>(
          flat, 256, 4, node, 256, 4, nullptr, nullptr, PeWab, e_b1, nullptr,
          nullptr, nullptr, nullptr, nullptr, nullptr, nullptr, Sb, nullptr, nullptr, 0);
    gemmT<4, EP_NONE, 0, 0><<<dim3(112, 4), 256, 0, stream>>>(
        flat, 256, 4, nullptr, 0, 0, nullptr, nullptr, PeWc, nullptr, nullptr,
        nullptr, nullptr, nullptr, nullptr, nullptr, nullptr, Tb, nullptr, nullptr, 0);
    // edge layer 2 raw + partials; stats; LN+relu+sum6 into SS (rows < 7168)
    for (int ch = 0; ch < nc; ++ch) {
      gemmT<4, EP_RAWP, 1, 0><<<dim3(epc / 64, 4), 256, 0, stream>>>(
          nullptr, 0, 8, nullptr, 0, 0, Sb, Tb, PeW2, e_b2, nullptr,
          nullptr, nullptr, nullptr, nullptr, nullptr, nullptr,
          H2raw, nullptr, PartE, ch * epc);
      rowstats<<<(epc + 255) / 256, 256, 0, stream>>>(PartE, muE, rsdE, epc);
      h2_sum_ln<<<(spc * 7 * 128) / 256, 256, 0, stream>>>(
          H2raw, muE, rsdE, e_g, e_bn, SS + (size_t)ch * spc * 7 * 512, spc * 7);
    }
    // node L1 (agg GEMM folded in): relu(flat@W1f + SS@M + b1 + [m<7168]v6 + av)
    gemmT<4, EP_NL1, 0, 0><<<dim3(128, 4), 256, 0, stream>>>(
        flat, 256, 4, SS, 512, 8, nullptr, nullptr, PnW1M, n_b1, v6,
        (round == 0) ? action : nullptr, n_w1,
        nullptr, nullptr, nullptr, nullptr, G, nullptr, nullptr, 0);
    // node L2 raw + partials: G -> G (in-place, same-rows safe); stats
    gemmT<4, EP_RAWP, 0, 0><<<dim3(128, 4), 256, 0, stream>>>(
        G, 512, 8, nullptr, 0, 0, nullptr, nullptr, PnW2, n_b2, nullptr,
        nullptr, nullptr, nullptr, nullptr, nullptr, nullptr, G, nullptr, PartN, 0);
    rowstats<<<32, 256, 0, stream>>>(PartN, muN, rsdN, 8192);
    // node L3 (+LN on staging) + residual: G -> node, flat +=
    gemmT<2, EP_NL3, 0, 1><<<dim3(128, 2), 256, 0, stream>>>(
        G, 512, 8, nullptr, 0, 0, nullptr, nullptr, PnW3, n_b3, nullptr,
        nullptr, nullptr, muN, rsdN, n_g, n_bn, node, flat, nullptr, 0);
  }
}